// Round 6
// baseline (230.694 us; speedup 1.0000x reference)
//
#include <hip/hip_runtime.h>
#include <math.h>

// PixPro fused masked all-pairs cosine loss, MI355X (gfx950).
// B=2048, C=256, H=W=7 -> P=49 pixels.
// out[b] = -(1/2401) * sum_{p,q} wt[p][q] * dot(base_p, mom_q)/max(nb_p*nm_q, eps)
// wt[p][q] = [base_A[p,q]==1] + [moment_A[q,p]==1].
//
// v8 = v7 (MFMA split-bf16) + decoupled load pipeline:
//  - 3-deep register prefetch (sets xA/xB/xC hold panels k..k+2); the set
//    consumed at step k was issued at step k-2 -> ~2 compute phases of
//    latency cover instead of v7's <1.
//  - raw counted barriers in the k-loop: s_waitcnt lgkmcnt(0) + s_barrier
//    (+ sched_barrier(0)). LDS write->read visibility preserved; global
//    loads stay in flight ACROSS barriers (no compiler vmcnt(0) drain --
//    the T4 mechanism). WAR on the double buffer covered by the lgkm drain
//    (it waits reads as well as writes).
//  - schedule fully unrolled with statically-named sets (no runtime
//    indexing -> no scratch; r1/r4 spills both came from dynamic indexing
//    or forced-low VGPR caps).
//  - everything else identical to v7: per-batch D = base^T.mom (49x49,
//    K=256) via mfma_f32_16x16x32_bf16, hi/lo split (Ahi.Bhi + Ahi.Blo +
//    Alo.Bhi), pixel-major LDS mats at PW=40, lane<->pixel transposed
//    gathers, norms fused into the conversion pass.

constexpr int NB  = 2048;
constexpr int NC  = 256;
constexpr int NP  = 49;
constexpr float EPS = 1e-6f;

constexpr int PW      = 40;                  // shorts per LDS matrix row (80 B)
constexpr int MROW    = 49;                  // real rows per matrix
constexpr int BUFROWS = 4 * MROW;            // 196 rows per k-panel buffer
constexpr int TOTROWS = 2 * BUFROWS + 15;    // + tail pad for tile-3 overflow reads

typedef short bf16x8 __attribute__((ext_vector_type(8)));   // 8 bf16 = 4 VGPR
typedef float f32x4  __attribute__((ext_vector_type(4)));   // mfma accumulator

__global__ __launch_bounds__(256, 2)
void pixpro_kernel(const float* __restrict__ gbase,
                   const float* __restrict__ gmom,
                   const int*   __restrict__ A1,
                   const int*   __restrict__ A2,
                   float*       __restrict__ out)
{
    __shared__ unsigned char wtb[NP * NP];                    // weights u8 {0,1,2}
    __shared__ __align__(16) unsigned short mats[TOTROWS * PW];
    __shared__ float nbp[4][NP], nmp[4][NP];                  // per-wave norm partials
    __shared__ float sbc[NP], smc[NP];                        // combined sq-norms
    __shared__ float redsum[4];

    const int tid  = threadIdx.x;
    const int wave = tid >> 6;
    const int lane = tid & 63;
    const int b    = blockIdx.x;

    // --- stage combined mask weights ---
    for (int t = tid; t < NP * NP; t += 256) {
        int p = t / NP, q = t - p * NP;
        wtb[t] = (unsigned char)((A1[t] == 1 ? 1 : 0) + (A2[q * NP + p] == 1 ? 1 : 0));
    }

    const float* gB = gbase + (size_t)b * (NC * NP);
    const float* gM = gmom  + (size_t)b * (NC * NP);
    const bool   ld = (lane < NP);

    float nrmb = 0.f, nrmm = 0.f;

    // issue the 16 scalar gathers for a panel (wave w: channels 32*panel+8w..+7)
    auto LOADS = [&](int panel, float (&x)[2][8]) {
        if (!ld) return;
        const float* pB = gB + (32 * panel + 8 * wave) * NP + lane;
        const float* pM = gM + (32 * panel + 8 * wave) * NP + lane;
        #pragma unroll
        for (int j = 0; j < 8; ++j) x[0][j] = pB[j * NP];
        #pragma unroll
        for (int j = 0; j < 8; ++j) x[1][j] = pM[j * NP];
    };

    // split hi/lo, accumulate norms, write one b128 per matrix
    auto CVTWRITE = [&](int buf, float (&x)[2][8]) {
        if (!ld) return;
        #pragma unroll
        for (int f = 0; f < 2; ++f) {
            unsigned int hi[4], lo[4];
            float n = 0.f;
            #pragma unroll
            for (int jp = 0; jp < 4; ++jp) {
                float x0 = x[f][2 * jp], x1 = x[f][2 * jp + 1];
                unsigned int u0 = __float_as_uint(x0) & 0xFFFF0000u;
                unsigned int u1 = __float_as_uint(x1) & 0xFFFF0000u;
                hi[jp] = u1 | (u0 >> 16);                 // packed bf16 pair (hi)
                float l0 = x0 - __uint_as_float(u0);      // exact residual
                float l1 = x1 - __uint_as_float(u1);
                unsigned int r;
                asm("v_cvt_pk_bf16_f32 %0, %1, %2" : "=v"(r) : "v"(l0), "v"(l1));
                lo[jp] = r;                               // packed bf16 pair (lo)
                n = fmaf(x0, x0, fmaf(x1, x1, n));        // fp32 norm (exact data)
            }
            if (f == 0) nrmb += n; else nrmm += n;
            unsigned short* mh = mats + ((size_t)buf * BUFROWS + (2 * f + 0) * MROW + lane) * PW + 8 * wave;
            unsigned short* ml = mats + ((size_t)buf * BUFROWS + (2 * f + 1) * MROW + lane) * PW + 8 * wave;
            *reinterpret_cast<uint4*>(mh) = make_uint4(hi[0], hi[1], hi[2], hi[3]);
            *reinterpret_cast<uint4*>(ml) = make_uint4(lo[0], lo[1], lo[2], lo[3]);
        }
    };

    f32x4 acc[4];
    const f32x4 zz = {0.f, 0.f, 0.f, 0.f};
    acc[0] = zz; acc[1] = zz; acc[2] = zz; acc[3] = zz;

    const int fr = lane & 15;     // frag row/col within tile
    const int kc = lane >> 4;     // k-chunk (8 bf16 each)

    auto COMPUTE = [&](int buf) {
        const unsigned short* mb = mats + (size_t)buf * BUFROWS * PW;
        // A-frag: A[m = 16w+fr][k = 8*kc .. +7]  (pixel-major row read)
        const unsigned short* pA = mb + (16 * wave + fr) * PW + kc * 8;
        bf16x8 Ah = *(const bf16x8*)(pA);
        bf16x8 Al = *(const bf16x8*)(pA + MROW * PW);
        #pragma unroll
        for (int t = 0; t < 4; ++t) {
            // B-frag: B[k = 8*kc..+7][n = 16t+fr] = momT[16t+fr][k]
            const unsigned short* pBm = mb + (2 * MROW + 16 * t + fr) * PW + kc * 8;
            bf16x8 Bh = *(const bf16x8*)(pBm);
            bf16x8 Bl = *(const bf16x8*)(pBm + MROW * PW);
            acc[t] = __builtin_amdgcn_mfma_f32_16x16x32_bf16(Ah, Bh, acc[t], 0, 0, 0);
            acc[t] = __builtin_amdgcn_mfma_f32_16x16x32_bf16(Ah, Bl, acc[t], 0, 0, 0);
            acc[t] = __builtin_amdgcn_mfma_f32_16x16x32_bf16(Al, Bh, acc[t], 0, 0, 0);
        }
    };

    // counted barrier: LDS visibility without draining in-flight global loads
    auto CBAR = [&]() {
        asm volatile("s_waitcnt lgkmcnt(0)" ::: "memory");
        __builtin_amdgcn_s_barrier();
        __builtin_amdgcn_sched_barrier(0);
    };

    // --- 3-deep prologue: issue panels 0,1,2; stage panel 0 ---
    float xA[2][8], xB[2][8], xC[2][8];
    LOADS(0, xA);
    LOADS(1, xB);
    LOADS(2, xC);
    CVTWRITE(0, xA);          // waits only xA's 16 loads (vmcnt counted)
    CBAR();

    // --- 8 k-steps, fully unrolled rotating schedule ---
    // step k: COMPUTE(panel k from buf k&1); issue panel k+3; stage panel k+1.
    COMPUTE(0); LOADS(3, xA); CVTWRITE(1, xB); CBAR();   // k=0
    COMPUTE(1); LOADS(4, xB); CVTWRITE(0, xC); CBAR();   // k=1
    COMPUTE(0); LOADS(5, xC); CVTWRITE(1, xA); CBAR();   // k=2
    COMPUTE(1); LOADS(6, xA); CVTWRITE(0, xB); CBAR();   // k=3
    COMPUTE(0); LOADS(7, xB); CVTWRITE(1, xC); CBAR();   // k=4
    COMPUTE(1);               CVTWRITE(0, xA); CBAR();   // k=5
    COMPUTE(0);               CVTWRITE(1, xB); CBAR();   // k=6
    COMPUTE(1);                                          // k=7

    // --- combine norms ---
    if (ld) { nbp[wave][lane] = nrmb; nmp[wave][lane] = nrmm; }
    __syncthreads();
    if (wave == 0 && ld) {
        sbc[lane] = nbp[0][lane] + nbp[1][lane] + nbp[2][lane] + nbp[3][lane];
        smc[lane] = nmp[0][lane] + nmp[1][lane] + nmp[2][lane] + nmp[3][lane];
    }
    __syncthreads();

    // --- epilogue: lane holds D[16w + 4*kc + r][16t + fr] in acc[t][r] ---
    float nbr[4];
    #pragma unroll
    for (int r = 0; r < 4; ++r) {
        int row = 16 * wave + 4 * kc + r;
        nbr[r] = (row < NP) ? sqrtf(sbc[row]) : 0.f;
    }
    float sum = 0.f;
    #pragma unroll
    for (int t = 0; t < 4; ++t) {
        int col = 16 * t + fr;
        if (col < NP) {
            float nmc = sqrtf(smc[col]);
            #pragma unroll
            for (int r = 0; r < 4; ++r) {
                int row = 16 * wave + 4 * kc + r;
                if (row < NP) {
                    float w     = (float)wtb[row * NP + col];
                    float denom = fmaxf(nbr[r] * nmc, EPS);
                    sum += w * acc[t][r] / denom;
                }
            }
        }
    }
    #pragma unroll
    for (int m = 32; m; m >>= 1) sum += __shfl_xor(sum, m, 64);
    if (lane == 0) redsum[wave] = sum;
    __syncthreads();
    if (tid == 0)
        out[b] = -(redsum[0] + redsum[1] + redsum[2] + redsum[3]) * (1.0f / 2401.0f);
}

extern "C" void kernel_launch(void* const* d_in, const int* in_sizes, int n_in,
                              void* d_out, int out_size, void* d_ws, size_t ws_size,
                              hipStream_t stream)
{
    (void)in_sizes; (void)n_in; (void)d_ws; (void)ws_size; (void)out_size;
    const float* base = (const float*)d_in[0];
    const float* mom  = (const float*)d_in[1];
    const int*   A1   = (const int*)d_in[2];
    const int*   A2   = (const int*)d_in[3];
    float*       out  = (float*)d_out;

    pixpro_kernel<<<NB, 256, 0, stream>>>(base, mom, A1, A2, out);
}

// Round 7
// 228.532 us; speedup vs baseline: 1.0095x; 1.0095x over previous
//
#include <hip/hip_runtime.h>
#include <math.h>

// PixPro fused masked all-pairs cosine loss, MI355X (gfx950).
// B=2048, C=256, H=W=7 -> P=49 pixels.
// out[b] = -(1/2401) * sum_{p,q} wt[p][q] * dot(base_p, mom_q)/max(nb_p*nm_q, eps)
// wt[p][q] = [base_A[p,q]==1] + [moment_A[q,p]==1].
//
// v9 = v7 (MFMA split-bf16) + FORCED load batching.
//  Post-mortem of v7/v8 (both 87us, both VGPR=52): the compiler rescheduled
//  the 16 stride-49 gathers down to their individual uses in CVTWRITE
//  (pressure heuristic), serializing ~16 memory latencies per k-step.
//  v8's 3-deep schedule was flattened the same way (48 in-flight regs can't
//  exist in 52 VGPRs, and there was no spill).
//  Fix:
//   - sched_barrier(0) fences pin each 16-load gather cluster at step top;
//     conversion/consumption stays below the fence.
//   - loads are unconditional (lanes>=49 read clamped pixel-48 address ->
//     broadcast within already-fetched lines); only LDS writes predicated.
//     No exec-masked branch region around the loads.
//   - depth-2 named register sets xX/xY: consume distance ~1 full step
//     (>= L3 latency); ~95 VGPRs total, under the 128 cap, no spill.
//  Everything else identical to v7: per-batch D = base^T.mom (49x49, K=256)
//  via mfma_f32_16x16x32_bf16, hi/lo split (3 mfma), pixel-major LDS mats
//  at PW=40, lgkm-only counted barriers (no vmcnt drain in loop).

constexpr int NB  = 2048;
constexpr int NC  = 256;
constexpr int NP  = 49;
constexpr float EPS = 1e-6f;

constexpr int PW      = 40;                  // shorts per LDS matrix row (80 B)
constexpr int MROW    = 49;                  // real rows per matrix
constexpr int BUFROWS = 4 * MROW;            // 196 rows per k-panel buffer
constexpr int TOTROWS = 2 * BUFROWS + 15;    // + tail pad for tile-3 overflow reads

typedef short bf16x8 __attribute__((ext_vector_type(8)));   // 8 bf16 = 4 VGPR
typedef float f32x4  __attribute__((ext_vector_type(4)));   // mfma accumulator

__global__ __launch_bounds__(256, 2)
void pixpro_kernel(const float* __restrict__ gbase,
                   const float* __restrict__ gmom,
                   const int*   __restrict__ A1,
                   const int*   __restrict__ A2,
                   float*       __restrict__ out)
{
    __shared__ unsigned char wtb[NP * NP];                    // weights u8 {0,1,2}
    __shared__ __align__(16) unsigned short mats[TOTROWS * PW];
    __shared__ float nbp[4][NP], nmp[4][NP];                  // per-wave norm partials
    __shared__ float sbc[NP], smc[NP];                        // combined sq-norms
    __shared__ float redsum[4];

    const int tid  = threadIdx.x;
    const int wave = tid >> 6;
    const int lane = tid & 63;
    const int b    = blockIdx.x;

    // --- stage combined mask weights ---
    for (int t = tid; t < NP * NP; t += 256) {
        int p = t / NP, q = t - p * NP;
        wtb[t] = (unsigned char)((A1[t] == 1 ? 1 : 0) + (A2[q * NP + p] == 1 ? 1 : 0));
    }

    const bool ld = (lane < NP);
    const int  px = ld ? lane : 48;           // clamped pixel for lanes 49-63

    const float* gBl = gbase + (size_t)b * (NC * NP) + px;
    const float* gMl = gmom  + (size_t)b * (NC * NP) + px;

    float nrmb = 0.f, nrmm = 0.f;

    // 16 stride-49 gathers for a panel (wave w: channels 32*panel+8w..+7).
    // Unconditional: all 64 lanes load (clamped px) -> straight-line cluster.
    auto LOADS = [&](int panel, float (&x)[2][8]) {
        const float* pB = gBl + (32 * panel + 8 * wave) * NP;
        const float* pM = gMl + (32 * panel + 8 * wave) * NP;
        #pragma unroll
        for (int j = 0; j < 8; ++j) x[0][j] = pB[j * NP];
        #pragma unroll
        for (int j = 0; j < 8; ++j) x[1][j] = pM[j * NP];
    };

    // split hi/lo, accumulate norms, write one b128 per matrix (writes predicated)
    auto CVTWRITE = [&](int buf, float (&x)[2][8]) {
        #pragma unroll
        for (int f = 0; f < 2; ++f) {
            unsigned int hi[4], lo[4];
            float n = 0.f;
            #pragma unroll
            for (int jp = 0; jp < 4; ++jp) {
                float x0 = x[f][2 * jp], x1 = x[f][2 * jp + 1];
                unsigned int u0 = __float_as_uint(x0) & 0xFFFF0000u;
                unsigned int u1 = __float_as_uint(x1) & 0xFFFF0000u;
                hi[jp] = u1 | (u0 >> 16);                 // packed bf16 pair (hi)
                float l0 = x0 - __uint_as_float(u0);      // exact residual
                float l1 = x1 - __uint_as_float(u1);
                unsigned int r;
                asm("v_cvt_pk_bf16_f32 %0, %1, %2" : "=v"(r) : "v"(l0), "v"(l1));
                lo[jp] = r;                               // packed bf16 pair (lo)
                n = fmaf(x0, x0, fmaf(x1, x1, n));        // fp32 norm (exact data)
            }
            if (f == 0) nrmb += n; else nrmm += n;
            if (ld) {
                unsigned short* mh = mats + ((size_t)buf * BUFROWS + (2 * f + 0) * MROW + lane) * PW + 8 * wave;
                unsigned short* ml = mats + ((size_t)buf * BUFROWS + (2 * f + 1) * MROW + lane) * PW + 8 * wave;
                *reinterpret_cast<uint4*>(mh) = make_uint4(hi[0], hi[1], hi[2], hi[3]);
                *reinterpret_cast<uint4*>(ml) = make_uint4(lo[0], lo[1], lo[2], lo[3]);
            }
        }
    };

    f32x4 acc[4];
    const f32x4 zz = {0.f, 0.f, 0.f, 0.f};
    acc[0] = zz; acc[1] = zz; acc[2] = zz; acc[3] = zz;

    const int fr = lane & 15;     // frag row/col within tile
    const int kc = lane >> 4;     // k-chunk (8 bf16 each)

    auto COMPUTE = [&](int buf) {
        const unsigned short* mb = mats + (size_t)buf * BUFROWS * PW;
        // A-frag: A[m = 16w+fr][k = 8*kc .. +7]  (pixel-major row read)
        const unsigned short* pA = mb + (16 * wave + fr) * PW + kc * 8;
        bf16x8 Ah = *(const bf16x8*)(pA);
        bf16x8 Al = *(const bf16x8*)(pA + MROW * PW);
        #pragma unroll
        for (int t = 0; t < 4; ++t) {
            // B-frag: B[k = 8*kc..+7][n = 16t+fr] = momT[16t+fr][k]
            const unsigned short* pBm = mb + (2 * MROW + 16 * t + fr) * PW + kc * 8;
            bf16x8 Bh = *(const bf16x8*)(pBm);
            bf16x8 Bl = *(const bf16x8*)(pBm + MROW * PW);
            acc[t] = __builtin_amdgcn_mfma_f32_16x16x32_bf16(Ah, Bh, acc[t], 0, 0, 0);
            acc[t] = __builtin_amdgcn_mfma_f32_16x16x32_bf16(Ah, Bl, acc[t], 0, 0, 0);
            acc[t] = __builtin_amdgcn_mfma_f32_16x16x32_bf16(Al, Bh, acc[t], 0, 0, 0);
        }
    };

    // counted barrier: LDS visibility without draining in-flight global loads
    auto CBAR = [&]() {
        asm volatile("s_waitcnt lgkmcnt(0)" ::: "memory");
        __builtin_amdgcn_s_barrier();
        __builtin_amdgcn_sched_barrier(0);
    };
    auto SB = [&]() { __builtin_amdgcn_sched_barrier(0); };

    // --- prologue: batched loads for panels 0,1; stage panel 0 ---
    float xX[2][8], xY[2][8];
    SB(); LOADS(0, xX); SB(); LOADS(1, xY); SB();
    CVTWRITE(0, xX);          // counted vmcnt wait: only xX's 16 loads
    CBAR();

    // --- 8 k-steps; gather cluster pinned at step top, depth-2 consume ---
    SB(); LOADS(2, xX); SB(); COMPUTE(0); CVTWRITE(1, xY); CBAR();   // k=0
    SB(); LOADS(3, xY); SB(); COMPUTE(1); CVTWRITE(0, xX); CBAR();   // k=1
    SB(); LOADS(4, xX); SB(); COMPUTE(0); CVTWRITE(1, xY); CBAR();   // k=2
    SB(); LOADS(5, xY); SB(); COMPUTE(1); CVTWRITE(0, xX); CBAR();   // k=3
    SB(); LOADS(6, xX); SB(); COMPUTE(0); CVTWRITE(1, xY); CBAR();   // k=4
    SB(); LOADS(7, xY); SB(); COMPUTE(1); CVTWRITE(0, xX); CBAR();   // k=5
    COMPUTE(0); CVTWRITE(1, xY); CBAR();                             // k=6
    COMPUTE(1);                                                      // k=7

    // --- combine norms ---
    if (ld) { nbp[wave][lane] = nrmb; nmp[wave][lane] = nrmm; }
    __syncthreads();
    if (wave == 0 && ld) {
        sbc[lane] = nbp[0][lane] + nbp[1][lane] + nbp[2][lane] + nbp[3][lane];
        smc[lane] = nmp[0][lane] + nmp[1][lane] + nmp[2][lane] + nmp[3][lane];
    }
    __syncthreads();

    // --- epilogue: lane holds D[16w + 4*kc + r][16t + fr] in acc[t][r] ---
    float nbr[4];
    #pragma unroll
    for (int r = 0; r < 4; ++r) {
        int row = 16 * wave + 4 * kc + r;
        nbr[r] = (row < NP) ? sqrtf(sbc[row]) : 0.f;
    }
    float sum = 0.f;
    #pragma unroll
    for (int t = 0; t < 4; ++t) {
        int col = 16 * t + fr;
        if (col < NP) {
            float nmc = sqrtf(smc[col]);
            #pragma unroll
            for (int r = 0; r < 4; ++r) {
                int row = 16 * wave + 4 * kc + r;
                if (row < NP) {
                    float w     = (float)wtb[row * NP + col];
                    float denom = fmaxf(nbr[r] * nmc, EPS);
                    sum += w * acc[t][r] / denom;
                }
            }
        }
    }
    #pragma unroll
    for (int m = 32; m; m >>= 1) sum += __shfl_xor(sum, m, 64);
    if (lane == 0) redsum[wave] = sum;
    __syncthreads();
    if (tid == 0)
        out[b] = -(redsum[0] + redsum[1] + redsum[2] + redsum[3]) * (1.0f / 2401.0f);
}

extern "C" void kernel_launch(void* const* d_in, const int* in_sizes, int n_in,
                              void* d_out, int out_size, void* d_ws, size_t ws_size,
                              hipStream_t stream)
{
    (void)in_sizes; (void)n_in; (void)d_ws; (void)ws_size; (void)out_size;
    const float* base = (const float*)d_in[0];
    const float* mom  = (const float*)d_in[1];
    const int*   A1   = (const int*)d_in[2];
    const int*   A2   = (const int*)d_in[3];
    float*       out  = (float*)d_out;

    pixpro_kernel<<<NB, 256, 0, stream>>>(base, mom, A1, A2, out);
}